// Round 4
// baseline (82.315 us; speedup 1.0000x reference)
//
#include <hip/hip_runtime.h>
#include <math.h>

// Problem constants (fixed by reference setup_inputs)
#define NN 32768
#define LL 256      // K dimension (leaves)
#define CC 64       // output cols (classes)
#define EPSV 1e-12f
#define SP 65       // padded LDS row stride in floats (65 -> bank = (row+col)%32, 2-way max)

typedef __attribute__((ext_vector_type(8))) _Float16 half8;  // MFMA A/B frag (4 VGPRs)
typedef __attribute__((ext_vector_type(4))) float f32x4;     // MFMA C/D frag

// ---------------------------------------------------------------------------
// Single fused kernel: out = log( clamp(mu,eps) @ softmax_rows(scores) )
//   - 512 blocks x 256 threads (4 waves); wave computes 16 rows x 64 cols.
//   - Each block redundantly computes the 256x64 softmax (scores is 64 KB,
//     L2-hot) -- cheaper than a separate serialized prep launch in the graph.
//   - Numeric scheme: single-term fp16 MFMA (A and B rel err ~2^-12 each ->
//     log abs err ~5e-4, threshold is 2.16e-2).
//   - Phases: issue mu A-loads -> stage scores->LDS -> row softmax ->
//     gather B-frags to regs -> write frags to LDS (aliased over dead scores)
//     -> MFMA hot loop -> log epilogue.
// ---------------------------------------------------------------------------
__global__ __launch_bounds__(256, 2) void fused_leaf_mix_kernel(
    const float* __restrict__ mu, const float* __restrict__ scores,
    float* __restrict__ out) {
    // 256*SP floats (scores/exp values, padded) + 256 floats (1/rowsum).
    // B-fragment region (32 regions x 64 lanes x 16 B = 32 KB) aliases the
    // front of S after S is dead.
    __shared__ __align__(16) unsigned char smem[256 * SP * 4 + 256 * 4];
    float* S = (float*)smem;
    float* rinv = (float*)(smem + 256 * SP * 4);
    half8* F = (half8*)smem;   // aliased over S (used after S is dead)

    const int tid = threadIdx.x;
    const int wid = tid >> 6;
    const int lane = tid & 63;
    const int quad = lane >> 4;
    const int m = lane & 15;

    // ---- issue scores loads (L2-hot after first generation) ----
    const float4* s4 = (const float4*)scores;
    float4 sv[16];
    #pragma unroll
    for (int i = 0; i < 16; ++i) sv[i] = s4[tid + 256 * i];

    // ---- issue mu A-frag loads early; consumed only in the hot loop ----
    // lane m holds row (wid*16 + m); k window = s*32 + quad*8 + j, j=0..7
    const size_t row = (size_t)blockIdx.x * 64 + wid * 16 + m;
    const float* arow = mu + row * LL + quad * 8;
    float4 a[16];
    #pragma unroll
    for (int s = 0; s < 8; ++s) {
        a[2 * s]     = *(const float4*)(arow + s * 32);
        a[2 * s + 1] = *(const float4*)(arow + s * 32 + 4);
    }

    // ---- stage scores into padded LDS rows (scalar stores, 2-way max) ----
    #pragma unroll
    for (int i = 0; i < 16; ++i) {
        const int f = tid + 256 * i;
        const int r = f >> 4;          // 16 float4 per 64-col row
        const int c4 = f & 15;
        S[r * SP + c4 * 4 + 0] = sv[i].x;
        S[r * SP + c4 * 4 + 1] = sv[i].y;
        S[r * SP + c4 * 4 + 2] = sv[i].z;
        S[r * SP + c4 * 4 + 3] = sv[i].w;
    }
    __syncthreads();

    // ---- row-per-thread softmax: thread t owns leaf-row t ----
    {
        float rv[64];
        #pragma unroll
        for (int c = 0; c < 64; ++c) rv[c] = S[tid * SP + c];
        float mx = rv[0];
        #pragma unroll
        for (int c = 1; c < 64; ++c) mx = fmaxf(mx, rv[c]);
        float sum = 0.f;
        #pragma unroll
        for (int c = 0; c < 64; ++c) { rv[c] = expf(rv[c] - mx); sum += rv[c]; }
        #pragma unroll
        for (int c = 0; c < 64; ++c) S[tid * SP + c] = rv[c];   // unnormalized e
        rinv[tid] = 1.0f / sum;
    }
    __syncthreads();

    // ---- gather this wave's 8 B-frag regions into registers ----
    // region g = s*4 + tn: lane (quad,m) holds B[k = s*32+quad*8+j][n = tn*16+m]
    half8 breg[8];
    #pragma unroll
    for (int i = 0; i < 8; ++i) {
        const int g = wid * 8 + i;
        const int s = g >> 2, tn = g & 3;
        #pragma unroll
        for (int j = 0; j < 8; ++j) {
            const int k = s * 32 + quad * 8 + j;
            breg[i][j] = (_Float16)(S[k * SP + tn * 16 + m] * rinv[k]);
        }
    }
    __syncthreads();   // all S reads done -> safe to overwrite with F

    #pragma unroll
    for (int i = 0; i < 8; ++i) F[(wid * 8 + i) * 64 + lane] = breg[i];
    __syncthreads();

    // ---- MFMA hot loop: 8 k-steps x 4 col-tiles, single-term fp16 ----
    f32x4 acc[4] = {{0.f, 0.f, 0.f, 0.f}, {0.f, 0.f, 0.f, 0.f},
                    {0.f, 0.f, 0.f, 0.f}, {0.f, 0.f, 0.f, 0.f}};
    #pragma unroll
    for (int s = 0; s < 8; ++s) {
        const float f8[8] = {a[2 * s].x, a[2 * s].y, a[2 * s].z, a[2 * s].w,
                             a[2 * s + 1].x, a[2 * s + 1].y, a[2 * s + 1].z, a[2 * s + 1].w};
        half8 ah;
        #pragma unroll
        for (int e = 0; e < 8; ++e) ah[e] = (_Float16)fmaxf(f8[e], EPSV);
        #pragma unroll
        for (int t = 0; t < 4; ++t) {
            const half8 b = F[(s * 4 + t) * 64 + lane];
            acc[t] = __builtin_amdgcn_mfma_f32_16x16x32_f16(ah, b, acc[t], 0, 0, 0);
        }
    }

    // ---- epilogue: C/D layout col = lane&15, row = quad*4 + reg ----
    const size_t outRow0 = (size_t)blockIdx.x * 64 + wid * 16 + quad * 4;
    #pragma unroll
    for (int t = 0; t < 4; ++t)
        #pragma unroll
        for (int r = 0; r < 4; ++r)
            out[(outRow0 + r) * CC + t * 16 + m] = logf(acc[t][r]);
}

extern "C" void kernel_launch(void* const* d_in, const int* in_sizes, int n_in,
                              void* d_out, int out_size, void* d_ws, size_t ws_size,
                              hipStream_t stream) {
    const float* mu     = (const float*)d_in[0];   // (32768, 256) f32
    const float* scores = (const float*)d_in[1];   // (256, 64)    f32
    float* out = (float*)d_out;                    // (32768, 64)  f32
    (void)d_ws; (void)ws_size;

    fused_leaf_mix_kernel<<<NN / 64, 256, 0, stream>>>(mu, scores, out);
}

// Round 5
// 78.440 us; speedup vs baseline: 1.0494x; 1.0494x over previous
//
#include <hip/hip_runtime.h>
#include <math.h>

// Problem constants (fixed by reference setup_inputs)
#define NN 32768
#define LL 256      // K dimension (leaves)
#define CC 64       // output cols (classes)
#define EPSV 1e-12f

typedef __attribute__((ext_vector_type(8))) _Float16 half8;  // MFMA A/B frag (4 VGPRs)
typedef __attribute__((ext_vector_type(4))) float f32x4;     // MFMA C/D frag

// ---------------------------------------------------------------------------
// Prep kernel: softmax(leaf_scores) rows -> fp16, scattered directly into
// MFMA B-fragment order for mfma_f32_16x16x32_f16.
//   B-frag: lane (q,m) holds B[k = s*32 + q*8 + j][n = t*16 + m], j = 0..7.
//   ws region (s,t): 64 lanes x 8 fp16 = 1 KB; 32 regions = 32 KB total.
// Grid: 256 blocks (one leaf-row each) x 64 threads (one class each).
// ---------------------------------------------------------------------------
__global__ __launch_bounds__(64) void prep_kernel(
    const float* __restrict__ scores, _Float16* __restrict__ wsB) {
    const int l = blockIdx.x;    // leaf row
    const int k = threadIdx.x;   // class col
    float v = scores[(size_t)l * CC + k];
    float mx = v;
    #pragma unroll
    for (int off = 32; off > 0; off >>= 1) mx = fmaxf(mx, __shfl_xor(mx, off));
    float e = expf(v - mx);
    float sum = e;
    #pragma unroll
    for (int off = 32; off > 0; off >>= 1) sum += __shfl_xor(sum, off);
    _Float16 h = (_Float16)(e / sum);

    const int s = l >> 5;          // k-step
    const int w = l & 31;
    const int q = w >> 3;          // quad within frag
    const int j = w & 7;           // element within frag
    const int t = k >> 4;          // n-tile
    const int m = k & 15;          // n within tile
    // fp16 index: region*(64 lanes * 8) + lane*8 + j
    wsB[((s * 4 + t) * 64 + q * 16 + m) * 8 + j] = h;
}

// ---------------------------------------------------------------------------
// Main kernel: out = log( clamp(mu,eps) @ Q )  via single-term fp16 MFMA
// (A and B truncation each rel ~2^-11..2^-12 -> log abs err ~5e-4, threshold
// 2.16e-2 -- verified empirically in R4, absmax 3.9e-3).
// 512 blocks x 256 threads (4 waves). Wave: 16 rows x 64 cols, full K=256.
// Bs = 32 KB (one copy from ws per block, L2-hot); A-frags loaded
// global->reg first so HBM latency overlaps Bs staging + barrier.
// ---------------------------------------------------------------------------
__global__ __launch_bounds__(256) void leaf_mix_mfma_kernel(
    const float* __restrict__ mu, const float4* __restrict__ wsB,
    float* __restrict__ out) {
    __shared__ float Bs[8192];   // 32 KB of pre-swizzled fp16 B fragments

    const int tid = threadIdx.x;
    const int wid = tid >> 6;
    const int lane = tid & 63;
    const int quad = lane >> 4;
    const int m = lane & 15;

    // ---- A loads first (HBM): lane m holds row, k-window = s*32 + quad*8 ----
    const size_t row = (size_t)blockIdx.x * 64 + wid * 16 + m;
    const float* arow = mu + row * LL + quad * 8;
    float4 a[16];
    #pragma unroll
    for (int s = 0; s < 8; ++s) {
        a[2 * s]     = *(const float4*)(arow + s * 32);
        a[2 * s + 1] = *(const float4*)(arow + s * 32 + 4);
    }

    // ---- stage Bs (32 KB from ws, L2-hot): 256 thr x 8 x 16 B ----
    {
        float4* dst = (float4*)Bs;
        #pragma unroll
        for (int i = 0; i < 8; ++i) dst[tid + 256 * i] = wsB[tid + 256 * i];
    }
    __syncthreads();

    f32x4 acc[4] = {{0.f, 0.f, 0.f, 0.f}, {0.f, 0.f, 0.f, 0.f},
                    {0.f, 0.f, 0.f, 0.f}, {0.f, 0.f, 0.f, 0.f}};

    #pragma unroll
    for (int s = 0; s < 8; ++s) {
        const float f8[8] = {a[2 * s].x, a[2 * s].y, a[2 * s].z, a[2 * s].w,
                             a[2 * s + 1].x, a[2 * s + 1].y, a[2 * s + 1].z, a[2 * s + 1].w};
        half8 ah;
        #pragma unroll
        for (int e = 0; e < 8; ++e) ah[e] = (_Float16)fmaxf(f8[e], EPSV);
        #pragma unroll
        for (int t = 0; t < 4; ++t) {
            const half8 b = ((const half8*)(Bs + (s * 4 + t) * 256))[lane];
            acc[t] = __builtin_amdgcn_mfma_f32_16x16x32_f16(ah, b, acc[t], 0, 0, 0);
        }
    }

    // ---- epilogue: C/D layout col = lane&15, row = quad*4 + reg ----
    const size_t outRow0 = (size_t)blockIdx.x * 64 + wid * 16 + quad * 4;
    #pragma unroll
    for (int t = 0; t < 4; ++t)
        #pragma unroll
        for (int r = 0; r < 4; ++r)
            out[(outRow0 + r) * CC + t * 16 + m] = logf(acc[t][r]);
}

extern "C" void kernel_launch(void* const* d_in, const int* in_sizes, int n_in,
                              void* d_out, int out_size, void* d_ws, size_t ws_size,
                              hipStream_t stream) {
    const float* mu     = (const float*)d_in[0];   // (32768, 256) f32
    const float* scores = (const float*)d_in[1];   // (256, 64)    f32
    float* out = (float*)d_out;                    // (32768, 64)  f32

    prep_kernel<<<LL, CC, 0, stream>>>(scores, (_Float16*)d_ws);
    leaf_mix_mfma_kernel<<<NN / 64, 256, 0, stream>>>(mu, (const float4*)d_ws, out);
}